// Round 9
// baseline (2286.645 us; speedup 1.0000x reference)
//
#include <hip/hip_runtime.h>
#include <stdint.h>

#define S_LEN 256
#define B_N 32
#define H_N 512
#define E_N 256
#define T_N 45
#define G4H 2048

typedef unsigned short u16;
typedef unsigned int u32;
typedef u16 u16x8 __attribute__((ext_vector_type(8)));
typedef u16 u16x4 __attribute__((ext_vector_type(4)));
typedef u32 u32x4 __attribute__((ext_vector_type(4)));
typedef __bf16 bf16x8 __attribute__((ext_vector_type(8)));
typedef float f32x4 __attribute__((ext_vector_type(4)));
typedef unsigned long long u64;

// ---------------- ws layout (bytes) ----------------
#define OFF_CLM   0ull                            // 256 B: claim counters [xcd0, xcd1, backup]
#define OFF_ATOK  256ull                          // 8192x256 bf16        = 4194304
#define OFF_WIHF  (OFF_ATOK + 4194304ull)         // 2048x256 bf16        = 1048576
#define OFF_WIHB  (OFF_WIHF + 1048576ull)
#define OFF_WHHF  (OFF_WIHB + 1048576ull)         // 2048x512 bf16        = 2097152
#define OFF_WHHB  (OFF_WHHF + 2097152ull)
#define OFF_WOUT  (OFF_WHHB + 2097152ull)         // 48x1024 bf16         = 98304
#define OFF_BSF   (OFF_WOUT + 98304ull)           // 2048 f32             = 8192
#define OFF_BSB   (OFF_BSF + 8192ull)
#define OFF_XPF   (OFF_BSB + 8192ull)             // 8192x2048 bf16       = 33554432
#define OFF_XPB   (OFF_XPF + 33554432ull)
#define OFF_HSF   (OFF_XPB + 33554432ull)         // 257x32x512 bf16      = 8421376 (local slab)
#define OFF_HSB   (OFF_HSF + 8421376ull)
#define OFF_HMF   (OFF_HSB + 8421376ull)          // mirror slab (sc1, device-coherent)
#define OFF_HMB   (OFF_HMF + 8421376ull)
#define OFF_EM    (OFF_HMB + 8421376ull)          // 8192x48 f32          = 1572864
#define OFF_VAL   (OFF_EM + 1572864ull)           // 32 f32

__device__ __forceinline__ u16 f2bf(float f) {
  union { float f; unsigned u; } v; v.f = f;
  unsigned r = v.u + 0x7FFFu + ((v.u >> 16) & 1u);
  return (u16)(r >> 16);
}
__device__ __forceinline__ float bf2f(u16 b) {
  union { unsigned u; float f; } v; v.u = ((unsigned)b) << 16;
  return v.f;
}
__device__ __forceinline__ bf16x8 ld8(const u16* p) {
  u16x8 v = *reinterpret_cast<const u16x8*>(p);
  return __builtin_bit_cast(bf16x8, v);
}
// plain 8B store: write-through to the producer's own XCD L2 (local fast path)
__device__ __forceinline__ void st_h8_l2(u16* p, u16x4 v) {
  __hip_atomic_store(reinterpret_cast<u64*>(p), __builtin_bit_cast(u64, v),
                     __ATOMIC_RELAXED, __HIP_MEMORY_SCOPE_WORKGROUP);
}
// agent-scope (sc1) 8B store: device coherence point (proven R8 substrate)
__device__ __forceinline__ void st_h8cc(u16* p, u16x4 v) {
  __hip_atomic_store(reinterpret_cast<u64*>(p), __builtin_bit_cast(u64, v),
                     __ATOMIC_RELAXED, __HIP_MEMORY_SCOPE_AGENT);
}
// 16B load, L1 bypass only -> reads this XCD's L2 (local fast path)
__device__ __forceinline__ u32x4 ld16l2(const u16* p) {
  u32x4 r;
  asm volatile("global_load_dwordx4 %0, %1, off sc0"
               : "=v"(r) : "v"(p) : "memory");
  return r;
}
// 16B load, L1+L2 bypass -> coherence point (mirror path)
__device__ __forceinline__ u32x4 ld16cc(const u16* p) {
  u32x4 r;
  asm volatile("global_load_dwordx4 %0, %1, off sc0 sc1"
               : "=v"(r) : "v"(p) : "memory");
  return r;
}
__device__ __forceinline__ f32x4 mfma16(bf16x8 a, bf16x8 b, f32x4 c) {
  return __builtin_amdgcn_mfma_f32_16x16x32_bf16(a, b, c, 0, 0, 0);
}
__device__ __forceinline__ float sigm(float x) { return 1.f / (1.f + __expf(-x)); }
__device__ __forceinline__ float tanhf_(float x) {
  float ax = fabsf(x);
  float e = __expf(-2.f * ax);
  float t = 1.f - 2.f * e / (1.f + e);
  return (x < 0.f) ? -t : t;
}
__device__ __forceinline__ float wredmax(float v) {
  #pragma unroll
  for (int m = 1; m < 64; m <<= 1) v = fmaxf(v, __shfl_xor(v, m));
  return v;
}
__device__ __forceinline__ float wredsum(float v) {
  #pragma unroll
  for (int m = 1; m < 64; m <<= 1) v += __shfl_xor(v, m);
  return v;
}

// ------------- embedding gather + bf16 cast: Atok[t=s*B+b][e] -------------
__global__ void k_castA(const int* __restrict__ x, const float* __restrict__ emb,
                        u16* __restrict__ atok) {
  int idx = blockIdx.x * 256 + threadIdx.x;   // 262144 threads, 8 elems each
  int t = idx >> 5;
  int e0 = (idx & 31) << 3;
  int s = t >> 5, b = t & 31;
  int xid = x[b * S_LEN + s];
  const float4* p = reinterpret_cast<const float4*>(emb + (size_t)xid * E_N + e0);
  float4 lo = p[0], hi = p[1];
  u16x8 o;
  o[0] = f2bf(lo.x); o[1] = f2bf(lo.y); o[2] = f2bf(lo.z); o[3] = f2bf(lo.w);
  o[4] = f2bf(hi.x); o[5] = f2bf(hi.y); o[6] = f2bf(hi.z); o[7] = f2bf(hi.w);
  *reinterpret_cast<u16x8*>(atok + (size_t)t * E_N + e0) = o;
}

// ------------- weight casts + bias sums + zero boundary slots -------------
__global__ void k_castW(const float* __restrict__ WihF, const float* __restrict__ WihB,
                        const float* __restrict__ WhhF, const float* __restrict__ WhhB,
                        const float* __restrict__ Wout,
                        const float* __restrict__ bihF, const float* __restrict__ bhhF,
                        const float* __restrict__ bihB, const float* __restrict__ bhhB,
                        u16* wihf, u16* wihb, u16* whhf, u16* whhb, u16* woutp,
                        float* bsf, float* bsb, u16* hsf, u16* hsb,
                        u16* hmf, u16* hmb) {
  int i = blockIdx.x * 256 + threadIdx.x;
  if (i < 524288) { wihf[i] = f2bf(WihF[i]); return; }
  i -= 524288;
  if (i < 524288) { wihb[i] = f2bf(WihB[i]); return; }
  i -= 524288;
  if (i < 1048576) { whhf[i] = f2bf(WhhF[i]); return; }
  i -= 1048576;
  if (i < 1048576) { whhb[i] = f2bf(WhhB[i]); return; }
  i -= 1048576;
  if (i < 49152) {
    int n = i >> 10, k = i & 1023;
    woutp[i] = (n < T_N) ? f2bf(Wout[n * 1024 + k]) : (u16)0;
    return;
  }
  i -= 49152;
  if (i < 2048) { bsf[i] = bihF[i] + bhhF[i]; return; }
  i -= 2048;
  if (i < 2048) { bsb[i] = bihB[i] + bhhB[i]; return; }
  i -= 2048;
  if (i < 16384) { hsf[i] = 0; return; }                       // hsF slot 0 = zeros
  i -= 16384;
  if (i < 16384) { hsb[(size_t)256 * 16384 + i] = 0; return; } // hsB slot S = zeros
  i -= 16384;
  if (i < 16384) { hmf[i] = 0; return; }                       // mirror boundaries
  i -= 16384;
  if (i < 16384) { hmb[(size_t)256 * 16384 + i] = 0; return; }
}

// ------------- input projection: xp_d[t][g] = Atok . Wih_d^T + bsum -------------
__global__ __launch_bounds__(256) void k_gemm_xp(
    const u16* __restrict__ atok, const u16* __restrict__ wihF, const u16* __restrict__ wihB,
    const float* __restrict__ bsF, const float* __restrict__ bsB,
    u16* __restrict__ xpF, u16* __restrict__ xpB) {
  int wid = blockIdx.x;
  int dir = wid >> 10, rem = wid & 1023;
  const int wave = threadIdx.x >> 6, lane = threadIdx.x & 63;
  const int lr = lane & 15, lh = lane >> 4;
  const int t0 = (rem >> 3) * 64;
  const int g0 = (rem & 7) * 256 + wave * 64;
  const u16* wih = dir ? wihB : wihF;
  const float* bs = dir ? bsB : bsF;
  u16* xp = dir ? xpB : xpF;
  f32x4 acc[4][4] = {};
  for (int kk = 0; kk < 8; ++kk) {
    int e = kk * 32 + lh * 8;
    bf16x8 a[4], bfr[4];
    #pragma unroll
    for (int mi = 0; mi < 4; ++mi) a[mi] = ld8(atok + (size_t)(t0 + 16 * mi + lr) * E_N + e);
    #pragma unroll
    for (int ni = 0; ni < 4; ++ni) bfr[ni] = ld8(wih + (size_t)(g0 + 16 * ni + lr) * E_N + e);
    #pragma unroll
    for (int mi = 0; mi < 4; ++mi)
      #pragma unroll
      for (int ni = 0; ni < 4; ++ni) acc[mi][ni] = mfma16(a[mi], bfr[ni], acc[mi][ni]);
  }
  #pragma unroll
  for (int ni = 0; ni < 4; ++ni) {
    int g = g0 + 16 * ni + lr;
    float bsv = bs[g];
    #pragma unroll
    for (int mi = 0; mi < 4; ++mi)
      #pragma unroll
      for (int r = 0; r < 4; ++r) {
        int t = t0 + 16 * mi + 4 * lh + r;
        xp[(size_t)t * G4H + g] = f2bf(acc[mi][ni][r] + bsv);
      }
  }
}

// ------------- bidirectional LSTM: XCD-pinned dataflow, dual-slab -------------
// Primaries: XCD0 claims fwd slots, XCD1 claims bwd slots (32 each). The per-step
// h all-to-all then stays in ONE XCD's coherent L2: plain stores + sc0 loads
// (~0.2us) instead of ~4us cross-XCD coherence-point visibility. Producers ALWAYS
// dual-store (plain local + sc1 mirror); consumers poll local for 3 rounds, then
// any pending fragment from the mirror (R8-proven). Backup pool staffs any
// direction whose claim counter misses 32 by a realtime deadline — duplicates are
// benign (bitwise-identical computation). Output is deterministic regardless of
// claim order. Sentinel protocol: 0xFFFFFFFF dword = impossible bf16 pair.
__global__ __launch_bounds__(128, 1) void k_lstm(
    const u16* __restrict__ whhF, const u16* __restrict__ whhB,
    const u16* __restrict__ xpF, const u16* __restrict__ xpB,
    u16* __restrict__ hsF, u16* __restrict__ hsB,
    u16* __restrict__ hmF, u16* __restrict__ hmB, int* claim) {
  __shared__ int sh_dir, sh_w, sh_fast;
  if (threadIdx.x == 0) {
    u32 xcc;
    asm volatile("s_getreg_b32 %0, hwreg(20, 0, 32)" : "=s"(xcc));
    xcc &= 7u;
    int dir = -1, w = -1, fast = 0;
    if (xcc <= 1u) {
      int r = __hip_atomic_fetch_add(&claim[xcc], 1, __ATOMIC_RELAXED,
                                     __HIP_MEMORY_SCOPE_AGENT);
      if (r < 32) { dir = (int)xcc; w = r; fast = 1; }
    }
    if (dir < 0) {
      int r2 = __hip_atomic_fetch_add(&claim[2], 1, __ATOMIC_RELAXED,
                                      __HIP_MEMORY_SCOPE_AGENT);
      if (r2 < 64) {
        int bd = r2 >> 5, bw = r2 & 31;
        u64 t0 = __builtin_amdgcn_s_memrealtime();
        for (;;) {
          int c = __hip_atomic_load(&claim[bd], __ATOMIC_RELAXED,
                                    __HIP_MEMORY_SCOPE_AGENT);
          if (c >= 32) break;                                   // staffed, not needed
          if (__builtin_amdgcn_s_memrealtime() - t0 > 50000ull) {
            dir = bd; w = bw; fast = 0; break;                  // cover the deficit
          }
          __builtin_amdgcn_s_sleep(8);
        }
      }
    }
    sh_dir = dir; sh_w = w; sh_fast = fast;
  }
  __syncthreads();
  const int dir = sh_dir, w = sh_w, fast = sh_fast;
  if (dir < 0) return;

  const int nt = threadIdx.x >> 6;     // wave: b-half
  const int lane = threadIdx.x & 63;
  const int lr = lane & 15, lh = lane >> 4;
  const u16* whh = dir ? whhB : whhF;
  const u16* xp = dir ? xpB : xpF;
  u16* hs = dir ? hsB : hsF;
  u16* hm = dir ? hmB : hmF;

  // Whh slice resident in registers: 4 gate-types x 16 k-steps
  bf16x8 A[4][16];
  #pragma unroll
  for (int mt = 0; mt < 4; ++mt) {
    const u16* base = whh + (size_t)(mt * 512 + 16 * w + lr) * H_N + lh * 8;
    #pragma unroll
    for (int kk = 0; kk < 16; ++kk) A[mt][kk] = ld8(base + kk * 32);
  }
  const int b = nt * 16 + lr;
  const int j0 = 16 * w + 4 * lh;
  float cst[4] = {0.f, 0.f, 0.f, 0.f};

  for (int t = 0; t < S_LEN; ++t) {
    const int s = dir ? (S_LEN - 1 - t) : t;
    const int slot_r = dir ? (s + 1) : s;
    const int slot_w = dir ? s : (s + 1);
    // xp prefetch (plain cached loads)
    u16x4 xq[4];
    const u16* xpt = xp + ((size_t)(s * B_N + b)) * G4H + j0;
    #pragma unroll
    for (int mt = 0; mt < 4; ++mt) xq[mt] = *reinterpret_cast<const u16x4*>(xpt + mt * 512);

    // h_{t-1}: local-first sweep, pending fragments escalate to the mirror
    const size_t rbase = ((size_t)slot_r * B_N + b) * H_N + lh * 8;
    const u16* hpl = hs + rbase;
    const u16* hpm = hm + rbase;
    u32x4 raw[16];
    if (fast) {
      #pragma unroll
      for (int kk = 0; kk < 16; ++kk) raw[kk] = ld16l2(hpl + kk * 32);
    } else {
      #pragma unroll
      for (int kk = 0; kk < 16; ++kk) raw[kk] = ld16cc(hpm + kk * 32);
    }
    asm volatile("s_waitcnt vmcnt(0)" ::: "memory");
    __builtin_amdgcn_sched_barrier(0);
    u32 pend = 0;
    #pragma unroll
    for (int kk = 0; kk < 16; ++kk)
      if (raw[kk][0] == 0xFFFFFFFFu || raw[kk][2] == 0xFFFFFFFFu) pend |= (1u << kk);
    int round = 1;
    while (__builtin_amdgcn_ballot_w64(pend != 0u)) {
      if (fast && round < 4) {
        #pragma unroll
        for (int kk = 0; kk < 16; ++kk)
          if (pend & (1u << kk)) raw[kk] = ld16l2(hpl + kk * 32);
      } else {
        #pragma unroll
        for (int kk = 0; kk < 16; ++kk)
          if (pend & (1u << kk)) raw[kk] = ld16cc(hpm + kk * 32);
      }
      asm volatile("s_waitcnt vmcnt(0)" ::: "memory");
      __builtin_amdgcn_sched_barrier(0);
      u32 np = 0;
      #pragma unroll
      for (int kk = 0; kk < 16; ++kk)
        if ((pend & (1u << kk)) &&
            (raw[kk][0] == 0xFFFFFFFFu || raw[kk][2] == 0xFFFFFFFFu)) np |= (1u << kk);
      pend = np;
      ++round;
    }

    f32x4 acc[4] = {};
    #pragma unroll
    for (int kk = 0; kk < 16; ++kk) {
      bf16x8 Bf = __builtin_bit_cast(bf16x8, raw[kk]);
      #pragma unroll
      for (int mt = 0; mt < 4; ++mt) acc[mt] = mfma16(A[mt][kk], Bf, acc[mt]);
    }
    u16x4 hv;
    #pragma unroll
    for (int r = 0; r < 4; ++r) {
      float gi = acc[0][r] + bf2f(xq[0][r]);
      float gf = acc[1][r] + bf2f(xq[1][r]);
      float gg = acc[2][r] + bf2f(xq[2][r]);
      float go = acc[3][r] + bf2f(xq[3][r]);
      float c = sigm(gf) * cst[r] + sigm(gi) * tanhf_(gg);
      cst[r] = c;
      hv[r] = f2bf(sigm(go) * tanhf_(c));
    }
    const size_t wbase = ((size_t)slot_w * B_N + b) * H_N + j0;
    st_h8_l2(hs + wbase, hv);            // local XCD L2 (fast readers)
    st_h8cc(hm + wbase, hv);             // coherence point (mirror readers)
  }
}

// ------------- emissions: em[t][tag] = [hsF|hsB] . Wout^T + bout -------------
__global__ __launch_bounds__(256) void k_gemm_em(
    const u16* __restrict__ hsF, const u16* __restrict__ hsB,
    const u16* __restrict__ woutp, const float* __restrict__ bout, float* __restrict__ em) {
  const int wave = threadIdx.x >> 6, lane = threadIdx.x & 63;
  const int lr = lane & 15, lh = lane >> 4;
  const int t0 = blockIdx.x * 64 + wave * 16;   // 128 WGs x 4 waves x 16 rows
  f32x4 acc[3] = {};
  for (int kk = 0; kk < 32; ++kk) {
    int k = kk * 32 + lh * 8;
    int t = t0 + lr;
    int s = t >> 5, bt = t & 31;
    const u16* ap = (kk < 16) ? (hsF + ((size_t)(s + 1) * B_N + bt) * H_N + k)
                              : (hsB + ((size_t)s * B_N + bt) * H_N + (k - 512));
    bf16x8 a = ld8(ap);
    #pragma unroll
    for (int ni = 0; ni < 3; ++ni) {
      bf16x8 bb = ld8(woutp + (size_t)(16 * ni + lr) * 1024 + k);
      acc[ni] = mfma16(a, bb, acc[ni]);
    }
  }
  #pragma unroll
  for (int ni = 0; ni < 3; ++ni) {
    int tag = 16 * ni + lr;
    float bo = (tag < T_N) ? bout[tag] : 0.f;
    #pragma unroll
    for (int r = 0; r < 4; ++r) {
      int t = t0 + 4 * lh + r;
      em[(size_t)t * 48 + tag] = acc[ni][r] + bo;
    }
  }
}

// ------------- CRF: one WAVE per batch element, shuffle-based -------------
__global__ __launch_bounds__(64) void k_crf(
    const float* __restrict__ em, const int* __restrict__ tags,
    const float* __restrict__ start, const float* __restrict__ endv,
    const float* __restrict__ trans, float* __restrict__ val) {
  __shared__ float tl[T_N * T_N + 32];
  const int b = blockIdx.x;
  const int lane = threadIdx.x;
  for (int i = lane; i < T_N * T_N + 32; i += 64)
    tl[i] = (i < T_N * T_N) ? trans[i] : 0.f;
  __syncthreads();
  float acur = (lane < T_N) ? (start[lane] + em[(size_t)b * 48 + lane]) : -1e30f;
  for (int s = 1; s < S_LEN; ++s) {
    float shift = wredmax(acur);
    float emv = (lane < 48) ? em[((size_t)s * B_N + b) * 48 + lane] : 0.f;
    float s0 = 0.f, s1 = 0.f, s2 = 0.f;
    #pragma unroll
    for (int t = 0; t < T_N; t += 3) {
      s0 += __expf(__shfl(acur, t)     + tl[t * T_N + lane]       - shift);
      s1 += __expf(__shfl(acur, t + 1) + tl[(t + 1) * T_N + lane] - shift);
      s2 += __expf(__shfl(acur, t + 2) + tl[(t + 2) * T_N + lane] - shift);
    }
    acur = (lane < T_N) ? (shift + __logf(s0 + s1 + s2) + emv) : -1e30f;
  }
  float z = (lane < T_N) ? (acur + endv[lane]) : -1e30f;
  float m = wredmax(z);
  float sum = wredsum((lane < T_N) ? __expf(z - m) : 0.f);
  float logZ = m + __logf(sum);
  float np = 0.f;
  #pragma unroll
  for (int q = 0; q < 4; ++q) {
    int s = 1 + lane * 4 + q;
    if (s < S_LEN) {
      int tp = tags[b * S_LEN + s - 1], tc = tags[b * S_LEN + s];
      np += tl[tp * T_N + tc] + em[((size_t)s * B_N + b) * 48 + tc];
    }
  }
  np = wredsum(np);
  if (lane == 0) {
    int tg0 = tags[b * S_LEN], tgL = tags[b * S_LEN + S_LEN - 1];
    float num = start[tg0] + em[(size_t)b * 48 + tg0] + np + endv[tgL];
    val[b] = num - logZ;
  }
}

__global__ void k_final(const float* __restrict__ val, float* __restrict__ out) {
  int lane = threadIdx.x & 63;
  float v = (lane < B_N) ? val[lane] : 0.f;
  v = wredsum(v);
  if (threadIdx.x == 0) out[0] = -(v / (float)B_N);
}

extern "C" void kernel_launch(void* const* d_in, const int* in_sizes, int n_in,
                              void* d_out, int out_size, void* d_ws, size_t ws_size,
                              hipStream_t stream) {
  const int* x = (const int*)d_in[0];
  const int* tags = (const int*)d_in[1];
  // d_in[2] = mask: all-ones by construction, unused
  const float* emb = (const float*)d_in[3];
  const float* WihF = (const float*)d_in[4];
  const float* WhhF = (const float*)d_in[5];
  const float* bihF = (const float*)d_in[6];
  const float* bhhF = (const float*)d_in[7];
  const float* WihB = (const float*)d_in[8];
  const float* WhhB = (const float*)d_in[9];
  const float* bihB = (const float*)d_in[10];
  const float* bhhB = (const float*)d_in[11];
  const float* Wout = (const float*)d_in[12];
  const float* bout = (const float*)d_in[13];
  const float* start = (const float*)d_in[14];
  const float* endv = (const float*)d_in[15];
  const float* trans = (const float*)d_in[16];
  float* out = (float*)d_out;
  char* ws = (char*)d_ws;

  u16* atok = (u16*)(ws + OFF_ATOK);
  u16* wihf = (u16*)(ws + OFF_WIHF);
  u16* wihb = (u16*)(ws + OFF_WIHB);
  u16* whhf = (u16*)(ws + OFF_WHHF);
  u16* whhb = (u16*)(ws + OFF_WHHB);
  u16* woutp = (u16*)(ws + OFF_WOUT);
  float* bsf = (float*)(ws + OFF_BSF);
  float* bsb = (float*)(ws + OFF_BSB);
  u16* xpf = (u16*)(ws + OFF_XPF);
  u16* xpb = (u16*)(ws + OFF_XPB);
  u16* hsf = (u16*)(ws + OFF_HSF);
  u16* hsb = (u16*)(ws + OFF_HSB);
  u16* hmf = (u16*)(ws + OFF_HMF);
  u16* hmb = (u16*)(ws + OFF_HMB);
  float* emis = (float*)(ws + OFF_EM);
  float* val = (float*)(ws + OFF_VAL);

  // claim counters + sentinel fills (both slabs), each launch (replay-safe)
  hipMemsetAsync(ws + OFF_CLM, 0, 256, stream);
  hipMemsetAsync(ws + OFF_HSF + 32768ull, 0xFF, 8388608ull, stream);
  hipMemsetAsync(ws + OFF_HSB, 0xFF, 8388608ull, stream);
  hipMemsetAsync(ws + OFF_HMF + 32768ull, 0xFF, 8388608ull, stream);
  hipMemsetAsync(ws + OFF_HMB, 0xFF, 8388608ull, stream);
  k_castA<<<1024, 256, 0, stream>>>(x, emb, atok);
  k_castW<<<12752, 256, 0, stream>>>(WihF, WihB, WhhF, WhhB, Wout, bihF, bhhF, bihB, bhhB,
                                     wihf, wihb, whhf, whhb, woutp, bsf, bsb, hsf, hsb,
                                     hmf, hmb);
  k_gemm_xp<<<2048, 256, 0, stream>>>(atok, wihf, wihb, bsf, bsb, xpf, xpb);
  k_lstm<<<768, 128, 0, stream>>>(whhf, whhb, xpf, xpb, hsf, hsb, hmf, hmb,
                                  (int*)(ws + OFF_CLM));
  k_gemm_em<<<128, 256, 0, stream>>>(hsf, hsb, woutp, bout, emis);
  k_crf<<<32, 64, 0, stream>>>(emis, tags, start, endv, trans, val);
  k_final<<<1, 64, 0, stream>>>(val, out);
}

// Round 10
// 2045.203 us; speedup vs baseline: 1.1181x; 1.1181x over previous
//
#include <hip/hip_runtime.h>
#include <stdint.h>

#define S_LEN 256
#define B_N 32
#define H_N 512
#define E_N 256
#define T_N 45
#define G4H 2048

typedef unsigned short u16;
typedef unsigned int u32;
typedef u16 u16x8 __attribute__((ext_vector_type(8)));
typedef u16 u16x4 __attribute__((ext_vector_type(4)));
typedef u32 u32x4 __attribute__((ext_vector_type(4)));
typedef __bf16 bf16x8 __attribute__((ext_vector_type(8)));
typedef float f32x4 __attribute__((ext_vector_type(4)));
typedef unsigned long long u64;

// ---------------- ws layout (bytes) ----------------
#define OFF_CLM   0ull                            // 256 B: claim counters [xcd0, xcd1, backup]
#define OFF_ATOK  256ull                          // 8192x256 bf16        = 4194304
#define OFF_WIHF  (OFF_ATOK + 4194304ull)         // 2048x256 bf16        = 1048576
#define OFF_WIHB  (OFF_WIHF + 1048576ull)
#define OFF_WHHF  (OFF_WIHB + 1048576ull)         // 2048x512 bf16        = 2097152
#define OFF_WHHB  (OFF_WHHF + 2097152ull)
#define OFF_WOUT  (OFF_WHHB + 2097152ull)         // 48x1024 bf16         = 98304
#define OFF_BSF   (OFF_WOUT + 98304ull)           // 2048 f32             = 8192
#define OFF_BSB   (OFF_BSF + 8192ull)
#define OFF_XPF   (OFF_BSB + 8192ull)             // 8192x2048 bf16       = 33554432
#define OFF_XPB   (OFF_XPF + 33554432ull)
#define OFF_HSF   (OFF_XPB + 33554432ull)         // 257x32x512 bf16      = 8421376 (local slab)
#define OFF_HSB   (OFF_HSF + 8421376ull)
#define OFF_HMF   (OFF_HSB + 8421376ull)          // mirror slab (sc1, device-coherent)
#define OFF_HMB   (OFF_HMF + 8421376ull)
#define OFF_EM    (OFF_HMB + 8421376ull)          // 8192x48 f32          = 1572864
#define OFF_VAL   (OFF_EM + 1572864ull)           // 32 f32

__device__ __forceinline__ u16 f2bf(float f) {
  union { float f; unsigned u; } v; v.f = f;
  unsigned r = v.u + 0x7FFFu + ((v.u >> 16) & 1u);
  return (u16)(r >> 16);
}
__device__ __forceinline__ float bf2f(u16 b) {
  union { unsigned u; float f; } v; v.u = ((unsigned)b) << 16;
  return v.f;
}
__device__ __forceinline__ bf16x8 ld8(const u16* p) {
  u16x8 v = *reinterpret_cast<const u16x8*>(p);
  return __builtin_bit_cast(bf16x8, v);
}
// sc0 8B store: scope-coherent write-through PAST L1 into this XCD's L2.
// (R4/R9 falsified plain stores: they stick in the write-back vector L1.)
__device__ __forceinline__ void st_h8_l2(u16* p, u16x4 v) {
  u64 q = __builtin_bit_cast(u64, v);
  asm volatile("global_store_dwordx2 %0, %1, off sc0"
               :: "v"(p), "v"(q) : "memory");
}
// agent-scope (sc1) 8B store: device coherence point (proven R8 substrate)
__device__ __forceinline__ void st_h8cc(u16* p, u16x4 v) {
  __hip_atomic_store(reinterpret_cast<u64*>(p), __builtin_bit_cast(u64, v),
                     __ATOMIC_RELAXED, __HIP_MEMORY_SCOPE_AGENT);
}
// 16B load, L1 bypass only -> reads this XCD's L2 (local fast path)
__device__ __forceinline__ u32x4 ld16l2(const u16* p) {
  u32x4 r;
  asm volatile("global_load_dwordx4 %0, %1, off sc0"
               : "=v"(r) : "v"(p) : "memory");
  return r;
}
// 16B load, L1+L2 bypass -> coherence point (mirror path)
__device__ __forceinline__ u32x4 ld16cc(const u16* p) {
  u32x4 r;
  asm volatile("global_load_dwordx4 %0, %1, off sc0 sc1"
               : "=v"(r) : "v"(p) : "memory");
  return r;
}
__device__ __forceinline__ f32x4 mfma16(bf16x8 a, bf16x8 b, f32x4 c) {
  return __builtin_amdgcn_mfma_f32_16x16x32_bf16(a, b, c, 0, 0, 0);
}
__device__ __forceinline__ float sigm(float x) { return 1.f / (1.f + __expf(-x)); }
__device__ __forceinline__ float tanhf_(float x) {
  float ax = fabsf(x);
  float e = __expf(-2.f * ax);
  float t = 1.f - 2.f * e / (1.f + e);
  return (x < 0.f) ? -t : t;
}
__device__ __forceinline__ float wredmax(float v) {
  #pragma unroll
  for (int m = 1; m < 64; m <<= 1) v = fmaxf(v, __shfl_xor(v, m));
  return v;
}
__device__ __forceinline__ float wredsum(float v) {
  #pragma unroll
  for (int m = 1; m < 64; m <<= 1) v += __shfl_xor(v, m);
  return v;
}

// ------------- embedding gather + bf16 cast: Atok[t=s*B+b][e] -------------
__global__ void k_castA(const int* __restrict__ x, const float* __restrict__ emb,
                        u16* __restrict__ atok) {
  int idx = blockIdx.x * 256 + threadIdx.x;   // 262144 threads, 8 elems each
  int t = idx >> 5;
  int e0 = (idx & 31) << 3;
  int s = t >> 5, b = t & 31;
  int xid = x[b * S_LEN + s];
  const float4* p = reinterpret_cast<const float4*>(emb + (size_t)xid * E_N + e0);
  float4 lo = p[0], hi = p[1];
  u16x8 o;
  o[0] = f2bf(lo.x); o[1] = f2bf(lo.y); o[2] = f2bf(lo.z); o[3] = f2bf(lo.w);
  o[4] = f2bf(hi.x); o[5] = f2bf(hi.y); o[6] = f2bf(hi.z); o[7] = f2bf(hi.w);
  *reinterpret_cast<u16x8*>(atok + (size_t)t * E_N + e0) = o;
}

// ------------- weight casts + bias sums + zero boundary slots -------------
__global__ void k_castW(const float* __restrict__ WihF, const float* __restrict__ WihB,
                        const float* __restrict__ WhhF, const float* __restrict__ WhhB,
                        const float* __restrict__ Wout,
                        const float* __restrict__ bihF, const float* __restrict__ bhhF,
                        const float* __restrict__ bihB, const float* __restrict__ bhhB,
                        u16* wihf, u16* wihb, u16* whhf, u16* whhb, u16* woutp,
                        float* bsf, float* bsb, u16* hsf, u16* hsb,
                        u16* hmf, u16* hmb) {
  int i = blockIdx.x * 256 + threadIdx.x;
  if (i < 524288) { wihf[i] = f2bf(WihF[i]); return; }
  i -= 524288;
  if (i < 524288) { wihb[i] = f2bf(WihB[i]); return; }
  i -= 524288;
  if (i < 1048576) { whhf[i] = f2bf(WhhF[i]); return; }
  i -= 1048576;
  if (i < 1048576) { whhb[i] = f2bf(WhhB[i]); return; }
  i -= 1048576;
  if (i < 49152) {
    int n = i >> 10, k = i & 1023;
    woutp[i] = (n < T_N) ? f2bf(Wout[n * 1024 + k]) : (u16)0;
    return;
  }
  i -= 49152;
  if (i < 2048) { bsf[i] = bihF[i] + bhhF[i]; return; }
  i -= 2048;
  if (i < 2048) { bsb[i] = bihB[i] + bhhB[i]; return; }
  i -= 2048;
  if (i < 16384) { hsf[i] = 0; return; }                       // hsF slot 0 = zeros
  i -= 16384;
  if (i < 16384) { hsb[(size_t)256 * 16384 + i] = 0; return; } // hsB slot S = zeros
  i -= 16384;
  if (i < 16384) { hmf[i] = 0; return; }                       // mirror boundaries
  i -= 16384;
  if (i < 16384) { hmb[(size_t)256 * 16384 + i] = 0; return; }
}

// ------------- input projection: xp_d[t][g] = Atok . Wih_d^T + bsum -------------
__global__ __launch_bounds__(256) void k_gemm_xp(
    const u16* __restrict__ atok, const u16* __restrict__ wihF, const u16* __restrict__ wihB,
    const float* __restrict__ bsF, const float* __restrict__ bsB,
    u16* __restrict__ xpF, u16* __restrict__ xpB) {
  int wid = blockIdx.x;
  int dir = wid >> 10, rem = wid & 1023;
  const int wave = threadIdx.x >> 6, lane = threadIdx.x & 63;
  const int lr = lane & 15, lh = lane >> 4;
  const int t0 = (rem >> 3) * 64;
  const int g0 = (rem & 7) * 256 + wave * 64;
  const u16* wih = dir ? wihB : wihF;
  const float* bs = dir ? bsB : bsF;
  u16* xp = dir ? xpB : xpF;
  f32x4 acc[4][4] = {};
  for (int kk = 0; kk < 8; ++kk) {
    int e = kk * 32 + lh * 8;
    bf16x8 a[4], bfr[4];
    #pragma unroll
    for (int mi = 0; mi < 4; ++mi) a[mi] = ld8(atok + (size_t)(t0 + 16 * mi + lr) * E_N + e);
    #pragma unroll
    for (int ni = 0; ni < 4; ++ni) bfr[ni] = ld8(wih + (size_t)(g0 + 16 * ni + lr) * E_N + e);
    #pragma unroll
    for (int mi = 0; mi < 4; ++mi)
      #pragma unroll
      for (int ni = 0; ni < 4; ++ni) acc[mi][ni] = mfma16(a[mi], bfr[ni], acc[mi][ni]);
  }
  #pragma unroll
  for (int ni = 0; ni < 4; ++ni) {
    int g = g0 + 16 * ni + lr;
    float bsv = bs[g];
    #pragma unroll
    for (int mi = 0; mi < 4; ++mi)
      #pragma unroll
      for (int r = 0; r < 4; ++r) {
        int t = t0 + 16 * mi + 4 * lh + r;
        xp[(size_t)t * G4H + g] = f2bf(acc[mi][ni][r] + bsv);
      }
  }
}

// ------------- bidirectional LSTM: XCD-pinned dataflow, sc0 dual-slab -------------
// Primaries: XCD0 claims fwd slots, XCD1 claims bwd (s_getreg HW_REG_XCC_ID). h
// exchange inside one XCD's L2: sc0 STORES (write-through past the write-back L1 —
// the single mechanism change this round) + sc0 loads. Producers always dual-store
// (sc0 local + sc1 mirror); consumers poll local for 2 rounds then escalate any
// pending fragment to the mirror (R8-proven), bounding the downside. Backup pool
// staffs an understaffed direction after a 30us realtime deadline; duplicates are
// benign (bitwise-identical computation). Sentinel: 0xFFFFFFFF dword.
__global__ __launch_bounds__(128, 1) void k_lstm(
    const u16* __restrict__ whhF, const u16* __restrict__ whhB,
    const u16* __restrict__ xpF, const u16* __restrict__ xpB,
    u16* __restrict__ hsF, u16* __restrict__ hsB,
    u16* __restrict__ hmF, u16* __restrict__ hmB, int* claim) {
  __shared__ int sh_dir, sh_w, sh_fast;
  if (threadIdx.x == 0) {
    u32 xcc;
    asm volatile("s_getreg_b32 %0, hwreg(20, 0, 32)" : "=s"(xcc));
    xcc &= 7u;
    int dir = -1, w = -1, fast = 0;
    if (xcc <= 1u) {
      int r = __hip_atomic_fetch_add(&claim[xcc], 1, __ATOMIC_RELAXED,
                                     __HIP_MEMORY_SCOPE_AGENT);
      if (r < 32) { dir = (int)xcc; w = r; fast = 1; }
    }
    if (dir < 0) {
      int r2 = __hip_atomic_fetch_add(&claim[2], 1, __ATOMIC_RELAXED,
                                      __HIP_MEMORY_SCOPE_AGENT);
      if (r2 < 64) {
        int bd = r2 >> 5, bw = r2 & 31;
        u64 t0 = __builtin_amdgcn_s_memrealtime();
        for (;;) {
          int c = __hip_atomic_load(&claim[bd], __ATOMIC_RELAXED,
                                    __HIP_MEMORY_SCOPE_AGENT);
          if (c >= 32) break;                                   // staffed, not needed
          if (__builtin_amdgcn_s_memrealtime() - t0 > 3000ull) {
            dir = bd; w = bw; fast = 0; break;                  // cover the deficit
          }
          __builtin_amdgcn_s_sleep(4);
        }
      }
    }
    sh_dir = dir; sh_w = w; sh_fast = fast;
  }
  __syncthreads();
  const int dir = sh_dir, w = sh_w, fast = sh_fast;
  if (dir < 0) return;

  const int nt = threadIdx.x >> 6;     // wave: b-half
  const int lane = threadIdx.x & 63;
  const int lr = lane & 15, lh = lane >> 4;
  const u16* whh = dir ? whhB : whhF;
  const u16* xp = dir ? xpB : xpF;
  u16* hs = dir ? hsB : hsF;
  u16* hm = dir ? hmB : hmF;

  // Whh slice resident in registers: 4 gate-types x 16 k-steps
  bf16x8 A[4][16];
  #pragma unroll
  for (int mt = 0; mt < 4; ++mt) {
    const u16* base = whh + (size_t)(mt * 512 + 16 * w + lr) * H_N + lh * 8;
    #pragma unroll
    for (int kk = 0; kk < 16; ++kk) A[mt][kk] = ld8(base + kk * 32);
  }
  const int b = nt * 16 + lr;
  const int j0 = 16 * w + 4 * lh;
  float cst[4] = {0.f, 0.f, 0.f, 0.f};

  for (int t = 0; t < S_LEN; ++t) {
    const int s = dir ? (S_LEN - 1 - t) : t;
    const int slot_r = dir ? (s + 1) : s;
    const int slot_w = dir ? s : (s + 1);
    // xp prefetch (plain cached loads)
    u16x4 xq[4];
    const u16* xpt = xp + ((size_t)(s * B_N + b)) * G4H + j0;
    #pragma unroll
    for (int mt = 0; mt < 4; ++mt) xq[mt] = *reinterpret_cast<const u16x4*>(xpt + mt * 512);

    // h_{t-1}: local-first sweep, pending fragments escalate to the mirror
    const size_t rbase = ((size_t)slot_r * B_N + b) * H_N + lh * 8;
    const u16* hpl = hs + rbase;
    const u16* hpm = hm + rbase;
    u32x4 raw[16];
    if (fast) {
      #pragma unroll
      for (int kk = 0; kk < 16; ++kk) raw[kk] = ld16l2(hpl + kk * 32);
    } else {
      #pragma unroll
      for (int kk = 0; kk < 16; ++kk) raw[kk] = ld16cc(hpm + kk * 32);
    }
    asm volatile("s_waitcnt vmcnt(0)" ::: "memory");
    __builtin_amdgcn_sched_barrier(0);
    u32 pend = 0;
    #pragma unroll
    for (int kk = 0; kk < 16; ++kk)
      if (raw[kk][0] == 0xFFFFFFFFu || raw[kk][2] == 0xFFFFFFFFu) pend |= (1u << kk);
    int round = 1;
    while (__builtin_amdgcn_ballot_w64(pend != 0u)) {
      if (fast && round < 3) {
        #pragma unroll
        for (int kk = 0; kk < 16; ++kk)
          if (pend & (1u << kk)) raw[kk] = ld16l2(hpl + kk * 32);
      } else {
        #pragma unroll
        for (int kk = 0; kk < 16; ++kk)
          if (pend & (1u << kk)) raw[kk] = ld16cc(hpm + kk * 32);
      }
      asm volatile("s_waitcnt vmcnt(0)" ::: "memory");
      __builtin_amdgcn_sched_barrier(0);
      u32 np = 0;
      #pragma unroll
      for (int kk = 0; kk < 16; ++kk)
        if ((pend & (1u << kk)) &&
            (raw[kk][0] == 0xFFFFFFFFu || raw[kk][2] == 0xFFFFFFFFu)) np |= (1u << kk);
      pend = np;
      ++round;
    }

    f32x4 acc[4] = {};
    #pragma unroll
    for (int kk = 0; kk < 16; ++kk) {
      bf16x8 Bf = __builtin_bit_cast(bf16x8, raw[kk]);
      #pragma unroll
      for (int mt = 0; mt < 4; ++mt) acc[mt] = mfma16(A[mt][kk], Bf, acc[mt]);
    }
    u16x4 hv;
    #pragma unroll
    for (int r = 0; r < 4; ++r) {
      float gi = acc[0][r] + bf2f(xq[0][r]);
      float gf = acc[1][r] + bf2f(xq[1][r]);
      float gg = acc[2][r] + bf2f(xq[2][r]);
      float go = acc[3][r] + bf2f(xq[3][r]);
      float c = sigm(gf) * cst[r] + sigm(gi) * tanhf_(gg);
      cst[r] = c;
      hv[r] = f2bf(sigm(go) * tanhf_(c));
    }
    const size_t wbase = ((size_t)slot_w * B_N + b) * H_N + j0;
    st_h8_l2(hs + wbase, hv);            // sc0: through L1 into local XCD L2
    st_h8cc(hm + wbase, hv);             // sc1: device coherence point (mirror)
  }
}

// ------------- emissions: em[t][tag] = [hsF|hsB] . Wout^T + bout -------------
__global__ __launch_bounds__(256) void k_gemm_em(
    const u16* __restrict__ hsF, const u16* __restrict__ hsB,
    const u16* __restrict__ woutp, const float* __restrict__ bout, float* __restrict__ em) {
  const int wave = threadIdx.x >> 6, lane = threadIdx.x & 63;
  const int lr = lane & 15, lh = lane >> 4;
  const int t0 = blockIdx.x * 64 + wave * 16;   // 128 WGs x 4 waves x 16 rows
  f32x4 acc[3] = {};
  for (int kk = 0; kk < 32; ++kk) {
    int k = kk * 32 + lh * 8;
    int t = t0 + lr;
    int s = t >> 5, bt = t & 31;
    const u16* ap = (kk < 16) ? (hsF + ((size_t)(s + 1) * B_N + bt) * H_N + k)
                              : (hsB + ((size_t)s * B_N + bt) * H_N + (k - 512));
    bf16x8 a = ld8(ap);
    #pragma unroll
    for (int ni = 0; ni < 3; ++ni) {
      bf16x8 bb = ld8(woutp + (size_t)(16 * ni + lr) * 1024 + k);
      acc[ni] = mfma16(a, bb, acc[ni]);
    }
  }
  #pragma unroll
  for (int ni = 0; ni < 3; ++ni) {
    int tag = 16 * ni + lr;
    float bo = (tag < T_N) ? bout[tag] : 0.f;
    #pragma unroll
    for (int r = 0; r < 4; ++r) {
      int t = t0 + 4 * lh + r;
      em[(size_t)t * 48 + tag] = acc[ni][r] + bo;
    }
  }
}

// ------------- CRF: one WAVE per batch element, shuffle-based -------------
__global__ __launch_bounds__(64) void k_crf(
    const float* __restrict__ em, const int* __restrict__ tags,
    const float* __restrict__ start, const float* __restrict__ endv,
    const float* __restrict__ trans, float* __restrict__ val) {
  __shared__ float tl[T_N * T_N + 32];
  const int b = blockIdx.x;
  const int lane = threadIdx.x;
  for (int i = lane; i < T_N * T_N + 32; i += 64)
    tl[i] = (i < T_N * T_N) ? trans[i] : 0.f;
  __syncthreads();
  float acur = (lane < T_N) ? (start[lane] + em[(size_t)b * 48 + lane]) : -1e30f;
  for (int s = 1; s < S_LEN; ++s) {
    float shift = wredmax(acur);
    float emv = (lane < 48) ? em[((size_t)s * B_N + b) * 48 + lane] : 0.f;
    float s0 = 0.f, s1 = 0.f, s2 = 0.f;
    #pragma unroll
    for (int t = 0; t < T_N; t += 3) {
      s0 += __expf(__shfl(acur, t)     + tl[t * T_N + lane]       - shift);
      s1 += __expf(__shfl(acur, t + 1) + tl[(t + 1) * T_N + lane] - shift);
      s2 += __expf(__shfl(acur, t + 2) + tl[(t + 2) * T_N + lane] - shift);
    }
    acur = (lane < T_N) ? (shift + __logf(s0 + s1 + s2) + emv) : -1e30f;
  }
  float z = (lane < T_N) ? (acur + endv[lane]) : -1e30f;
  float m = wredmax(z);
  float sum = wredsum((lane < T_N) ? __expf(z - m) : 0.f);
  float logZ = m + __logf(sum);
  float np = 0.f;
  #pragma unroll
  for (int q = 0; q < 4; ++q) {
    int s = 1 + lane * 4 + q;
    if (s < S_LEN) {
      int tp = tags[b * S_LEN + s - 1], tc = tags[b * S_LEN + s];
      np += tl[tp * T_N + tc] + em[((size_t)s * B_N + b) * 48 + tc];
    }
  }
  np = wredsum(np);
  if (lane == 0) {
    int tg0 = tags[b * S_LEN], tgL = tags[b * S_LEN + S_LEN - 1];
    float num = start[tg0] + em[(size_t)b * 48 + tg0] + np + endv[tgL];
    val[b] = num - logZ;
  }
}

__global__ void k_final(const float* __restrict__ val, float* __restrict__ out) {
  int lane = threadIdx.x & 63;
  float v = (lane < B_N) ? val[lane] : 0.f;
  v = wredsum(v);
  if (threadIdx.x == 0) out[0] = -(v / (float)B_N);
}

extern "C" void kernel_launch(void* const* d_in, const int* in_sizes, int n_in,
                              void* d_out, int out_size, void* d_ws, size_t ws_size,
                              hipStream_t stream) {
  const int* x = (const int*)d_in[0];
  const int* tags = (const int*)d_in[1];
  // d_in[2] = mask: all-ones by construction, unused
  const float* emb = (const float*)d_in[3];
  const float* WihF = (const float*)d_in[4];
  const float* WhhF = (const float*)d_in[5];
  const float* bihF = (const float*)d_in[6];
  const float* bhhF = (const float*)d_in[7];
  const float* WihB = (const float*)d_in[8];
  const float* WhhB = (const float*)d_in[9];
  const float* bihB = (const float*)d_in[10];
  const float* bhhB = (const float*)d_in[11];
  const float* Wout = (const float*)d_in[12];
  const float* bout = (const float*)d_in[13];
  const float* start = (const float*)d_in[14];
  const float* endv = (const float*)d_in[15];
  const float* trans = (const float*)d_in[16];
  float* out = (float*)d_out;
  char* ws = (char*)d_ws;

  u16* atok = (u16*)(ws + OFF_ATOK);
  u16* wihf = (u16*)(ws + OFF_WIHF);
  u16* wihb = (u16*)(ws + OFF_WIHB);
  u16* whhf = (u16*)(ws + OFF_WHHF);
  u16* whhb = (u16*)(ws + OFF_WHHB);
  u16* woutp = (u16*)(ws + OFF_WOUT);
  float* bsf = (float*)(ws + OFF_BSF);
  float* bsb = (float*)(ws + OFF_BSB);
  u16* xpf = (u16*)(ws + OFF_XPF);
  u16* xpb = (u16*)(ws + OFF_XPB);
  u16* hsf = (u16*)(ws + OFF_HSF);
  u16* hsb = (u16*)(ws + OFF_HSB);
  u16* hmf = (u16*)(ws + OFF_HMF);
  u16* hmb = (u16*)(ws + OFF_HMB);
  float* emis = (float*)(ws + OFF_EM);
  float* val = (float*)(ws + OFF_VAL);

  // claim counters + sentinel fills (both slabs), each launch (replay-safe)
  hipMemsetAsync(ws + OFF_CLM, 0, 256, stream);
  hipMemsetAsync(ws + OFF_HSF + 32768ull, 0xFF, 8388608ull, stream);
  hipMemsetAsync(ws + OFF_HSB, 0xFF, 8388608ull, stream);
  hipMemsetAsync(ws + OFF_HMF + 32768ull, 0xFF, 8388608ull, stream);
  hipMemsetAsync(ws + OFF_HMB, 0xFF, 8388608ull, stream);
  k_castA<<<1024, 256, 0, stream>>>(x, emb, atok);
  k_castW<<<12752, 256, 0, stream>>>(WihF, WihB, WhhF, WhhB, Wout, bihF, bhhF, bihB, bhhB,
                                     wihf, wihb, whhf, whhb, woutp, bsf, bsb, hsf, hsb,
                                     hmf, hmb);
  k_gemm_xp<<<2048, 256, 0, stream>>>(atok, wihf, wihb, bsf, bsb, xpf, xpb);
  k_lstm<<<768, 128, 0, stream>>>(whhf, whhb, xpf, xpb, hsf, hsb, hmf, hmb,
                                  (int*)(ws + OFF_CLM));
  k_gemm_em<<<128, 256, 0, stream>>>(hsf, hsb, woutp, bout, emis);
  k_crf<<<32, 64, 0, stream>>>(emis, tags, start, endv, trans, val);
  k_final<<<1, 64, 0, stream>>>(val, out);
}

// Round 11
// 1501.498 us; speedup vs baseline: 1.5229x; 1.3621x over previous
//
#include <hip/hip_runtime.h>
#include <stdint.h>

#define S_LEN 256
#define B_N 32
#define H_N 512
#define E_N 256
#define T_N 45
#define G4H 2048

typedef unsigned short u16;
typedef unsigned int u32;
typedef u16 u16x8 __attribute__((ext_vector_type(8)));
typedef u16 u16x4 __attribute__((ext_vector_type(4)));
typedef u32 u32x4 __attribute__((ext_vector_type(4)));
typedef u32 u32x2 __attribute__((ext_vector_type(2)));
typedef __bf16 bf16x8 __attribute__((ext_vector_type(8)));
typedef float f32x4 __attribute__((ext_vector_type(4)));
typedef unsigned long long u64;

// ---------------- ws layout (bytes) ----------------
#define OFF_ATOK  256ull                          // 8192x256 bf16        = 4194304
#define OFF_WIHF  (OFF_ATOK + 4194304ull)         // 2048x256 bf16        = 1048576
#define OFF_WIHB  (OFF_WIHF + 1048576ull)
#define OFF_WHHF  (OFF_WIHB + 1048576ull)         // 2048x512 bf16        = 2097152
#define OFF_WHHB  (OFF_WHHF + 2097152ull)
#define OFF_WOUT  (OFF_WHHB + 2097152ull)         // 48x1024 bf16         = 98304
#define OFF_BSF   (OFF_WOUT + 98304ull)           // 2048 f32             = 8192
#define OFF_BSB   (OFF_BSF + 8192ull)
#define OFF_XPF   (OFF_BSB + 8192ull)             // 8192x2048 bf16       = 33554432
#define OFF_XPB   (OFF_XPF + 33554432ull)
#define OFF_HSF   (OFF_XPB + 33554432ull)         // 257x32x512 bf16      = 8421376
#define OFF_HSB   (OFF_HSF + 8421376ull)
#define OFF_EM    (OFF_HSB + 8421376ull)          // 8192x48 f32          = 1572864

__device__ __forceinline__ u16 f2bf(float f) {
  union { float f; unsigned u; } v; v.f = f;
  unsigned r = v.u + 0x7FFFu + ((v.u >> 16) & 1u);
  return (u16)(r >> 16);
}
__device__ __forceinline__ float bf2f(u16 b) {
  union { unsigned u; float f; } v; v.u = ((unsigned)b) << 16;
  return v.f;
}
__device__ __forceinline__ bf16x8 ld8(const u16* p) {
  u16x8 v = *reinterpret_cast<const u16x8*>(p);
  return __builtin_bit_cast(bf16x8, v);
}
// agent-scope (sc1) 8B store: device coherence point (proven R2/R8 substrate)
__device__ __forceinline__ void st_h8cc(u16* p, u16x4 v) {
  __hip_atomic_store(reinterpret_cast<u64*>(p), __builtin_bit_cast(u64, v),
                     __ATOMIC_RELAXED, __HIP_MEMORY_SCOPE_AGENT);
}
// agent-scope 16B load (sc1 only — matches compiler's agent-atomic emission).
// NOT waited: caller must s_waitcnt vmcnt(0) + sched_barrier(0) (rule #18).
__device__ __forceinline__ u32x4 ld16cc(const u16* p) {
  u32x4 r;
  asm volatile("global_load_dwordx4 %0, %1, off sc1"
               : "=v"(r) : "v"(p) : "memory");
  return r;
}
__device__ __forceinline__ u32x2 ld8cc(const u16* p) {
  u32x2 r;
  asm volatile("global_load_dwordx2 %0, %1, off sc1"
               : "=v"(r) : "v"(p) : "memory");
  return r;
}
__device__ __forceinline__ void st2cc(u16* p, u32 v) {
  asm volatile("global_store_short %0, %1, off sc1"
               :: "v"(p), "v"(v) : "memory");
}
__device__ __forceinline__ f32x4 mfma16(bf16x8 a, bf16x8 b, f32x4 c) {
  return __builtin_amdgcn_mfma_f32_16x16x32_bf16(a, b, c, 0, 0, 0);
}
__device__ __forceinline__ float sigm(float x) { return 1.f / (1.f + __expf(-x)); }
__device__ __forceinline__ float tanhf_(float x) {
  float ax = fabsf(x);
  float e = __expf(-2.f * ax);
  float t = 1.f - 2.f * e / (1.f + e);
  return (x < 0.f) ? -t : t;
}
__device__ __forceinline__ float wredmax(float v) {
  #pragma unroll
  for (int m = 1; m < 64; m <<= 1) v = fmaxf(v, __shfl_xor(v, m));
  return v;
}
__device__ __forceinline__ float wredsum(float v) {
  #pragma unroll
  for (int m = 1; m < 64; m <<= 1) v += __shfl_xor(v, m);
  return v;
}

// ------------- fused embedding-gather + weight casts -------------
__global__ void k_castAW(const int* __restrict__ x, const float* __restrict__ emb,
                         u16* __restrict__ atok,
                         const float* __restrict__ WihF, const float* __restrict__ WihB,
                         const float* __restrict__ WhhF, const float* __restrict__ WhhB,
                         const float* __restrict__ Wout,
                         const float* __restrict__ bihF, const float* __restrict__ bhhF,
                         const float* __restrict__ bihB, const float* __restrict__ bhhB,
                         u16* wihf, u16* wihb, u16* whhf, u16* whhb, u16* woutp,
                         float* bsf, float* bsb, u16* hsf, u16* hsb) {
  int bid = blockIdx.x;
  if (bid < 1024) {                        // castA: Atok[t=s*B+b][e] bf16
    int idx = bid * 256 + threadIdx.x;
    int t = idx >> 5;
    int e0 = (idx & 31) << 3;
    int s = t >> 5, b = t & 31;
    int xid = x[b * S_LEN + s];
    const float4* p = reinterpret_cast<const float4*>(emb + (size_t)xid * E_N + e0);
    float4 lo = p[0], hi = p[1];
    u16x8 o;
    o[0] = f2bf(lo.x); o[1] = f2bf(lo.y); o[2] = f2bf(lo.z); o[3] = f2bf(lo.w);
    o[4] = f2bf(hi.x); o[5] = f2bf(hi.y); o[6] = f2bf(hi.z); o[7] = f2bf(hi.w);
    *reinterpret_cast<u16x8*>(atok + (size_t)t * E_N + e0) = o;
    return;
  }
  int i = (bid - 1024) * 256 + threadIdx.x;
  if (i < 524288) { wihf[i] = f2bf(WihF[i]); return; }
  i -= 524288;
  if (i < 524288) { wihb[i] = f2bf(WihB[i]); return; }
  i -= 524288;
  if (i < 1048576) { whhf[i] = f2bf(WhhF[i]); return; }
  i -= 1048576;
  if (i < 1048576) { whhb[i] = f2bf(WhhB[i]); return; }
  i -= 1048576;
  if (i < 49152) {
    int n = i >> 10, k = i & 1023;
    woutp[i] = (n < T_N) ? f2bf(Wout[n * 1024 + k]) : (u16)0;
    return;
  }
  i -= 49152;
  if (i < 2048) { bsf[i] = bihF[i] + bhhF[i]; return; }
  i -= 2048;
  if (i < 2048) { bsb[i] = bihB[i] + bhhB[i]; return; }
  i -= 2048;
  if (i < 16384) { hsf[i] = 0; return; }                       // hsF slot 0 = zeros
  i -= 16384;
  if (i < 16384) { hsb[(size_t)256 * 16384 + i] = 0; return; } // hsB slot S = zeros
}

// ------------- fused kernel: blocks 0-63 = LSTM dataflow; 64+ = xp GEMM -------------
// LSTM: R8 selective-re-poll substrate (proven 1128us), with (a) sc1-only polls
// (agent scope, matching the proven atomic primitives; was system sc0|sc1) and
// (b) s_sleep(1) backoff per re-poll round. xp: computed by trailing blocks on
// otherwise-idle CUs, earliest-needed tiles first (fwd s asc, bwd s desc,
// interleaved); published via sc1 2B stores; consumed via sc1 loads with the
// same impossible-NaN sentinel protocol (finite dot products can't be 0xFFFF).
// No deadlock: the 64 lstm blocks dispatch first; xp blocks always have slots.
__global__ __launch_bounds__(128, 1) void k_fused(
    const u16* __restrict__ whhF, const u16* __restrict__ whhB,
    const u16* __restrict__ atok,
    const u16* __restrict__ wihF, const u16* __restrict__ wihB,
    const float* __restrict__ bsF, const float* __restrict__ bsB,
    u16* __restrict__ xpF, u16* __restrict__ xpB,
    u16* __restrict__ hsF, u16* __restrict__ hsB) {
  if (blockIdx.x >= 64) {
    // ---------- xp GEMM tile: 64t x 128g per block (2 waves) ----------
    int j = (int)blockIdx.x - 64;        // 0..4095
    int dir = j & 1, idx = j >> 1;       // 2048 tiles per dir
    int tIdx = idx >> 4, gIdx = idx & 15;
    if (dir) tIdx = 127 - tIdx;          // bwd: s descending (needed first)
    const int wave = threadIdx.x >> 6, lane = threadIdx.x & 63;
    const int lr = lane & 15, lh = lane >> 4;
    const int t0 = tIdx * 64;
    const int g0 = gIdx * 128 + wave * 64;
    const u16* wih = dir ? wihB : wihF;
    const float* bs = dir ? bsB : bsF;
    u16* xp = dir ? xpB : xpF;
    f32x4 acc[4][4] = {};
    for (int kk = 0; kk < 8; ++kk) {
      int e = kk * 32 + lh * 8;
      bf16x8 a[4], bfr[4];
      #pragma unroll
      for (int mi = 0; mi < 4; ++mi) a[mi] = ld8(atok + (size_t)(t0 + 16 * mi + lr) * E_N + e);
      #pragma unroll
      for (int ni = 0; ni < 4; ++ni) bfr[ni] = ld8(wih + (size_t)(g0 + 16 * ni + lr) * E_N + e);
      #pragma unroll
      for (int mi = 0; mi < 4; ++mi)
        #pragma unroll
        for (int ni = 0; ni < 4; ++ni) acc[mi][ni] = mfma16(a[mi], bfr[ni], acc[mi][ni]);
    }
    #pragma unroll
    for (int ni = 0; ni < 4; ++ni) {
      int g = g0 + 16 * ni + lr;
      float bsv = bs[g];
      #pragma unroll
      for (int mi = 0; mi < 4; ++mi)
        #pragma unroll
        for (int r = 0; r < 4; ++r) {
          int t = t0 + 16 * mi + 4 * lh + r;
          st2cc(xp + (size_t)t * G4H + g, (u32)f2bf(acc[mi][ni][r] + bsv));
        }
    }
    return;
  }
  // ---------- LSTM dataflow (R8 substrate) ----------
  const int dir = blockIdx.x >> 5;
  const int w = blockIdx.x & 31;
  const int nt = threadIdx.x >> 6;     // wave: b-half
  const int lane = threadIdx.x & 63;
  const int lr = lane & 15, lh = lane >> 4;
  const u16* whh = dir ? whhB : whhF;
  const u16* xp = dir ? xpB : xpF;
  u16* hs = dir ? hsB : hsF;

  // Whh slice resident in registers: 4 gate-types x 16 k-steps
  bf16x8 A[4][16];
  #pragma unroll
  for (int mt = 0; mt < 4; ++mt) {
    const u16* base = whh + (size_t)(mt * 512 + 16 * w + lr) * H_N + lh * 8;
    #pragma unroll
    for (int kk = 0; kk < 16; ++kk) A[mt][kk] = ld8(base + kk * 32);
  }
  const int b = nt * 16 + lr;
  const int j0 = 16 * w + 4 * lh;
  float cst[4] = {0.f, 0.f, 0.f, 0.f};

  for (int t = 0; t < S_LEN; ++t) {
    const int s = dir ? (S_LEN - 1 - t) : t;
    const int slot_r = dir ? (s + 1) : s;
    const int slot_w = dir ? s : (s + 1);

    // xq: sc1 loads (xp produced in-grid); verified post-MFMA via NaN sentinel
    u32x2 xqr[4];
    const u16* xpt = xp + ((size_t)(s * B_N + b)) * G4H + j0;
    #pragma unroll
    for (int mt = 0; mt < 4; ++mt) xqr[mt] = ld8cc(xpt + mt * 512);

    // h_{t-1}: full sweep, then selective re-poll of pending fragments
    const u16* hp = hs + ((size_t)slot_r * B_N + b) * H_N + lh * 8;
    u32x4 raw[16];
    #pragma unroll
    for (int kk = 0; kk < 16; ++kk) raw[kk] = ld16cc(hp + kk * 32);
    asm volatile("s_waitcnt vmcnt(0)" ::: "memory");
    __builtin_amdgcn_sched_barrier(0);
    u32 pend = 0;
    #pragma unroll
    for (int kk = 0; kk < 16; ++kk)
      if (raw[kk][0] == 0xFFFFFFFFu || raw[kk][2] == 0xFFFFFFFFu) pend |= (1u << kk);
    while (__builtin_amdgcn_ballot_w64(pend != 0u)) {
      __builtin_amdgcn_s_sleep(1);
      #pragma unroll
      for (int kk = 0; kk < 16; ++kk)
        if (pend & (1u << kk)) raw[kk] = ld16cc(hp + kk * 32);   // exec-masked reload
      asm volatile("s_waitcnt vmcnt(0)" ::: "memory");
      __builtin_amdgcn_sched_barrier(0);
      u32 np = 0;
      #pragma unroll
      for (int kk = 0; kk < 16; ++kk)
        if ((pend & (1u << kk)) &&
            (raw[kk][0] == 0xFFFFFFFFu || raw[kk][2] == 0xFFFFFFFFu)) np |= (1u << kk);
      pend = np;
    }

    f32x4 acc[4] = {};
    #pragma unroll
    for (int kk = 0; kk < 16; ++kk) {
      bf16x8 Bf = __builtin_bit_cast(bf16x8, raw[kk]);
      #pragma unroll
      for (int mt = 0; mt < 4; ++mt) acc[mt] = mfma16(A[mt][kk], Bf, acc[mt]);
    }

    // verify xq arrived (rare miss: only the first steps of each direction)
    for (;;) {
      u32 xbad = 0;
      #pragma unroll
      for (int mt = 0; mt < 4; ++mt) {
        #pragma unroll
        for (int d = 0; d < 2; ++d) {
          u32 wv = xqr[mt][d];
          xbad |= ((wv & 0xFFFFu) == 0xFFFFu) | ((wv >> 16) == 0xFFFFu);
        }
      }
      if (!__builtin_amdgcn_ballot_w64(xbad != 0u)) break;
      __builtin_amdgcn_s_sleep(1);
      #pragma unroll
      for (int mt = 0; mt < 4; ++mt) xqr[mt] = ld8cc(xpt + mt * 512);
      asm volatile("s_waitcnt vmcnt(0)" ::: "memory");
      __builtin_amdgcn_sched_barrier(0);
    }

    u16x4 hv;
    #pragma unroll
    for (int r = 0; r < 4; ++r) {
      u32 w0 = xqr[0][r >> 1], w1 = xqr[1][r >> 1], w2 = xqr[2][r >> 1], w3 = xqr[3][r >> 1];
      u16 x0 = (r & 1) ? (u16)(w0 >> 16) : (u16)(w0 & 0xFFFFu);
      u16 x1 = (r & 1) ? (u16)(w1 >> 16) : (u16)(w1 & 0xFFFFu);
      u16 x2 = (r & 1) ? (u16)(w2 >> 16) : (u16)(w2 & 0xFFFFu);
      u16 x3 = (r & 1) ? (u16)(w3 >> 16) : (u16)(w3 & 0xFFFFu);
      float gi = acc[0][r] + bf2f(x0);
      float gf = acc[1][r] + bf2f(x1);
      float gg = acc[2][r] + bf2f(x2);
      float go = acc[3][r] + bf2f(x3);
      float c = sigm(gf) * cst[r] + sigm(gi) * tanhf_(gg);
      cst[r] = c;
      hv[r] = f2bf(sigm(go) * tanhf_(c));
    }
    st_h8cc(hs + ((size_t)slot_w * B_N + b) * H_N + j0, hv);  // fire-and-forget
  }
}

// ------------- emissions: em[t][tag] = [hsF|hsB] . Wout^T + bout -------------
__global__ __launch_bounds__(256) void k_gemm_em(
    const u16* __restrict__ hsF, const u16* __restrict__ hsB,
    const u16* __restrict__ woutp, const float* __restrict__ bout, float* __restrict__ em) {
  const int wave = threadIdx.x >> 6, lane = threadIdx.x & 63;
  const int lr = lane & 15, lh = lane >> 4;
  const int t0 = blockIdx.x * 64 + wave * 16;   // 128 WGs x 4 waves x 16 rows
  f32x4 acc[3] = {};
  for (int kk = 0; kk < 32; ++kk) {
    int k = kk * 32 + lh * 8;
    int t = t0 + lr;
    int s = t >> 5, bt = t & 31;
    const u16* ap = (kk < 16) ? (hsF + ((size_t)(s + 1) * B_N + bt) * H_N + k)
                              : (hsB + ((size_t)s * B_N + bt) * H_N + (k - 512));
    bf16x8 a = ld8(ap);
    #pragma unroll
    for (int ni = 0; ni < 3; ++ni) {
      bf16x8 bb = ld8(woutp + (size_t)(16 * ni + lr) * 1024 + k);
      acc[ni] = mfma16(a, bb, acc[ni]);
    }
  }
  #pragma unroll
  for (int ni = 0; ni < 3; ++ni) {
    int tag = 16 * ni + lr;
    float bo = (tag < T_N) ? bout[tag] : 0.f;
    #pragma unroll
    for (int r = 0; r < 4; ++r) {
      int t = t0 + 4 * lh + r;
      em[(size_t)t * 48 + tag] = acc[ni][r] + bo;
    }
  }
}

// ------------- CRF: one WAVE per batch element; final mean via atomicAdd -------------
__global__ __launch_bounds__(64) void k_crf(
    const float* __restrict__ em, const int* __restrict__ tags,
    const float* __restrict__ start, const float* __restrict__ endv,
    const float* __restrict__ trans, float* __restrict__ out) {
  __shared__ float tl[T_N * T_N + 32];
  const int b = blockIdx.x;
  const int lane = threadIdx.x;
  for (int i = lane; i < T_N * T_N + 32; i += 64)
    tl[i] = (i < T_N * T_N) ? trans[i] : 0.f;
  __syncthreads();
  float acur = (lane < T_N) ? (start[lane] + em[(size_t)b * 48 + lane]) : -1e30f;
  float emv_next = (lane < 48) ? em[((size_t)(1 * B_N + b)) * 48 + lane] : 0.f;
  for (int s = 1; s < S_LEN; ++s) {
    float shift = wredmax(acur);
    float emv = emv_next;
    if (s < S_LEN - 1)                    // software-pipelined em row load
      emv_next = (lane < 48) ? em[((size_t)((s + 1) * B_N + b)) * 48 + lane] : 0.f;
    float s0 = 0.f, s1 = 0.f, s2 = 0.f;
    #pragma unroll
    for (int t = 0; t < T_N; t += 3) {
      s0 += __expf(__shfl(acur, t)     + tl[t * T_N + lane]       - shift);
      s1 += __expf(__shfl(acur, t + 1) + tl[(t + 1) * T_N + lane] - shift);
      s2 += __expf(__shfl(acur, t + 2) + tl[(t + 2) * T_N + lane] - shift);
    }
    acur = (lane < T_N) ? (shift + __logf(s0 + s1 + s2) + emv) : -1e30f;
  }
  float z = (lane < T_N) ? (acur + endv[lane]) : -1e30f;
  float m = wredmax(z);
  float sum = wredsum((lane < T_N) ? __expf(z - m) : 0.f);
  float logZ = m + __logf(sum);
  float np = 0.f;
  #pragma unroll
  for (int q = 0; q < 4; ++q) {
    int s = 1 + lane * 4 + q;
    if (s < S_LEN) {
      int tp = tags[b * S_LEN + s - 1], tc = tags[b * S_LEN + s];
      np += tl[tp * T_N + tc] + em[((size_t)s * B_N + b) * 48 + tc];
    }
  }
  np = wredsum(np);
  if (lane == 0) {
    int tg0 = tags[b * S_LEN], tgL = tags[b * S_LEN + S_LEN - 1];
    float num = start[tg0] + em[(size_t)b * 48 + tg0] + np + endv[tgL];
    atomicAdd(out, -(num - logZ) / (float)B_N);
  }
}

extern "C" void kernel_launch(void* const* d_in, const int* in_sizes, int n_in,
                              void* d_out, int out_size, void* d_ws, size_t ws_size,
                              hipStream_t stream) {
  const int* x = (const int*)d_in[0];
  const int* tags = (const int*)d_in[1];
  // d_in[2] = mask: all-ones by construction, unused
  const float* emb = (const float*)d_in[3];
  const float* WihF = (const float*)d_in[4];
  const float* WhhF = (const float*)d_in[5];
  const float* bihF = (const float*)d_in[6];
  const float* bhhF = (const float*)d_in[7];
  const float* WihB = (const float*)d_in[8];
  const float* WhhB = (const float*)d_in[9];
  const float* bihB = (const float*)d_in[10];
  const float* bhhB = (const float*)d_in[11];
  const float* Wout = (const float*)d_in[12];
  const float* bout = (const float*)d_in[13];
  const float* start = (const float*)d_in[14];
  const float* endv = (const float*)d_in[15];
  const float* trans = (const float*)d_in[16];
  float* out = (float*)d_out;
  char* ws = (char*)d_ws;

  u16* atok = (u16*)(ws + OFF_ATOK);
  u16* wihf = (u16*)(ws + OFF_WIHF);
  u16* wihb = (u16*)(ws + OFF_WIHB);
  u16* whhf = (u16*)(ws + OFF_WHHF);
  u16* whhb = (u16*)(ws + OFF_WHHB);
  u16* woutp = (u16*)(ws + OFF_WOUT);
  float* bsf = (float*)(ws + OFF_BSF);
  float* bsb = (float*)(ws + OFF_BSB);
  u16* xpf = (u16*)(ws + OFF_XPF);
  u16* xpb = (u16*)(ws + OFF_XPB);
  u16* hsf = (u16*)(ws + OFF_HSF);
  u16* hsb = (u16*)(ws + OFF_HSB);
  float* emis = (float*)(ws + OFF_EM);

  // out accumulator + sentinel fills: hs (one contiguous 16MB span: fwd slots
  // 1..256 + bwd slots 0..255) and xp (both dirs, 64MB)
  hipMemsetAsync(out, 0, sizeof(float), stream);
  hipMemsetAsync(ws + OFF_HSF + 32768ull, 0xFF, 16777216ull, stream);
  hipMemsetAsync(ws + OFF_XPF, 0xFF, 67108864ull, stream);
  k_castAW<<<13648, 256, 0, stream>>>(x, emb, atok, WihF, WihB, WhhF, WhhB, Wout,
                                      bihF, bhhF, bihB, bhhB,
                                      wihf, wihb, whhf, whhb, woutp, bsf, bsb, hsf, hsb);
  k_fused<<<4160, 128, 0, stream>>>(whhf, whhb, atok, wihf, wihb, bsf, bsb,
                                    xpf, xpb, hsf, hsb);
  k_gemm_em<<<128, 256, 0, stream>>>(hsf, hsb, woutp, bout, emis);
  k_crf<<<32, 64, 0, stream>>>(emis, tags, start, endv, trans, out);
}